// Round 5
// baseline (625.291 us; speedup 1.0000x reference)
//
#include <hip/hip_runtime.h>
#include <hip/hip_bf16.h>

// ---------------- problem constants ----------------
#define NB 16384
#define NN 32
#define DK 275
#define HH 64
#define AA 14
#define Q_ELEMS   ((size_t)NB * NN * AA)
#define HID_ELEMS ((size_t)NB * NN * HH)

typedef unsigned short u16;
typedef unsigned int   u32;
typedef __attribute__((ext_vector_type(8))) short s8v;   // 8 bf16 (4 VGPR)
typedef __attribute__((ext_vector_type(4))) float f4v;   // MFMA acc

#define MFMA(a,b,c) __builtin_amdgcn_mfma_f32_16x16x32_bf16((a),(b),(c),0,0,0)

// native RNE f32->bf16 (pairs fuse to v_cvt_pk_bf16_f32)
__device__ __forceinline__ u16 bf_hi(float x){
    return __bfloat16_as_ushort(__float2bfloat16(x));
}
__device__ __forceinline__ float bf_f(u16 h){
    union{u32 u; float f;} v; v.u = ((u32)h) << 16; return v.f;
}

// ---------------- ws (prepacked weight fragments) ----------------
#define WSE_OFF 0
#define WSE_SZ  (2*4*9*1024)
#define WSL_SZ  (2*4*2*1024)
#define WSQN_OFF (WSE_SZ + 6*WSL_SZ)

__global__ void prepack_w(const float* __restrict__ We,
                          const float* __restrict__ Wv1, const float* __restrict__ Wk1, const float* __restrict__ Wq1,
                          const float* __restrict__ Wv2, const float* __restrict__ Wk2, const float* __restrict__ Wq2,
                          const float* __restrict__ Wqn, char* __restrict__ ws)
{
    int gid  = blockIdx.x * 256 + threadIdx.x;
    int slot = gid >> 6, lane = gid & 63;
    const float* W; int K, OUT, STEPS, MT; size_t base; int rem;
    if (slot < 72) { W = We; K = DK; OUT = 64; STEPS = 9; MT = 4; base = WSE_OFF; rem = slot; }
    else if (slot < 168) {
        int q = slot - 72; int mat = q >> 4; rem = q & 15;
        W = mat==0?Wv1 : mat==1?Wk1 : mat==2?Wq1 : mat==3?Wv2 : mat==4?Wk2 : Wq2;
        K = 64; OUT = 64; STEPS = 2; MT = 4; base = WSE_SZ + (size_t)mat * WSL_SZ;
    } else { W = Wqn; K = 64; OUT = AA; STEPS = 2; MT = 1; base = WSQN_OFF; rem = slot - 168; }
    int o  = 16 * (((rem / STEPS) % MT)) + (lane & 15);
    int part = (rem / STEPS) / MT;
    int s  = rem % STEPS;
    int kb = 32 * s + 8 * (lane >> 4);
    u16 h[8];
#pragma unroll
    for (int e = 0; e < 8; ++e) {
        int k = kb + e;
        float x = (k < K && o < OUT) ? W[(size_t)k * OUT + o] : 0.f;
        u16 hi = bf_hi(x);
        h[e] = (part == 0) ? hi : bf_hi(x - bf_f(hi));
    }
    uint4 d;
    d.x = (u32)h[0] | ((u32)h[1] << 16);
    d.y = (u32)h[2] | ((u32)h[3] << 16);
    d.z = (u32)h[4] | ((u32)h[5] << 16);
    d.w = (u32)h[6] | ((u32)h[7] << 16);
    *(uint4*)(ws + base + (size_t)rem * 1024 + (size_t)lane * 16) = d;
}

// ---------------- LDS layout (bytes) ----------------
// Overlay region [0, 26112):
//   staging A: XAHI 32x336, XALO 32x336 (k 0..159)
//   staging B: XBHI 32x272, XBLO 32x272 (k 160..287, zero-padded)
//   after encoder: QHI/QLO/KHI/KLO 32x144, VT 64x80 (1xbf16), P 32x80 (1xbf16)
#define SM_XAHI 0
#define SM_XALO 10752
#define SM_XBHI 0
#define SM_XBLO 8704
#define SM_QHI  0
#define SM_QLO  4608
#define SM_KHI  9216
#define SM_KLO  13824
#define SM_VT   18432
#define SM_P    23552
#define SM_HHI  26112
#define SM_HLO  30720
#define SM_TOT  35328

__device__ __forceinline__ f4v relu4(f4v v){
    f4v r; r[0]=fmaxf(v[0],0.f); r[1]=fmaxf(v[1],0.f);
    r[2]=fmaxf(v[2],0.f); r[3]=fmaxf(v[3],0.f); return r;
}
__device__ __forceinline__ void write_hl4(char* hp, char* lp, f4v v){
    u16 h0=bf_hi(v[0]), h1=bf_hi(v[1]), h2=bf_hi(v[2]), h3=bf_hi(v[3]);
    uint2 hw; hw.x = (u32)h0 | ((u32)h1<<16); hw.y = (u32)h2 | ((u32)h3<<16);
    u16 l0=bf_hi(v[0]-bf_f(h0)), l1=bf_hi(v[1]-bf_f(h1));
    u16 l2=bf_hi(v[2]-bf_f(h2)), l3=bf_hi(v[3]-bf_f(h3));
    uint2 lw; lw.x = (u32)l0 | ((u32)l1<<16); lw.y = (u32)l2 | ((u32)l3<<16);
    *(uint2*)hp = hw; *(uint2*)lp = lw;
}
__device__ __forceinline__ void stage4(char* hrow, char* lrow, int k0,
                                       float x0, float x1, float x2, float x3){
    u16 h0=bf_hi(x0), h1=bf_hi(x1), h2=bf_hi(x2), h3=bf_hi(x3);
    uint2 hw; hw.x=(u32)h0|((u32)h1<<16); hw.y=(u32)h2|((u32)h3<<16);
    u16 l0=bf_hi(x0-bf_f(h0)), l1=bf_hi(x1-bf_f(h1));
    u16 l2=bf_hi(x2-bf_f(h2)), l3=bf_hi(x3-bf_f(h3));
    uint2 lw; lw.x=(u32)l0|((u32)l1<<16); lw.y=(u32)l2|((u32)l3<<16);
    *(uint2*)(hrow + 2*k0) = hw; *(uint2*)(lrow + 2*k0) = lw;
}

__global__ __launch_bounds__(256, 4) void dgn_mfma(
    const float* __restrict__ X, const float* __restrict__ adj,
    const char*  __restrict__ ws,
    const float* __restrict__ b_enc,
    const float* __restrict__ bv1, const float* __restrict__ bk1, const float* __restrict__ bq1,
    const float* __restrict__ bv2, const float* __restrict__ bk2, const float* __restrict__ bq2,
    const float* __restrict__ bqn,
    float* __restrict__ Out)
{
    __shared__ __align__(16) char sm[SM_TOT];
    const int b = blockIdx.x, tid = threadIdx.x;
    const int w = tid >> 6, l = tid & 63, lr = l & 15, lg = l >> 4;
    const int ct  = w & 1;
    const int mt0 = w >> 1, mt1 = (w >> 1) + 2;
    const int agent = 16 * ct + lr;
    const char* wsl = ws + (size_t)l * 16;
    const int t8 = tid & 7, ag8 = tid >> 3;          // staging: 8 threads/agent
    const float* xrow = X + (size_t)b * NN * DK + (size_t)ag8 * DK;

    // ---- adj prefetch into registers (waves 0,1; hidden under staging/encoder) ----
    float adjm[4][2];
    if (w < 2) {
        const float* ar = adj + (size_t)b * NN * NN;
#pragma unroll
        for (int r = 0; r < 4; ++r) {
            int row = 16*w + 4*lg + r;
            adjm[r][0] = ar[row * 32 + lr];
            adjm[r][1] = ar[row * 32 + 16 + lr];
        }
    }

    // ---- stage X phase A (k 0..159) as bf16 hi/lo ----
    {
        char* hrow = sm + SM_XAHI + ag8 * 336;
        char* lrow = sm + SM_XALO + ag8 * 336;
#pragma unroll
        for (int it = 0; it < 5; ++it) {
            int k0 = 4 * t8 + 32 * it;               // 0..156
            stage4(hrow, lrow, k0, xrow[k0], xrow[k0+1], xrow[k0+2], xrow[k0+3]);
        }
    }
    __syncthreads();

    // ---- encoder phase A: s = 0..4 (split chains) ----
    f4v ehh0 = *(const f4v*)(b_enc + 16*mt0 + 4*lg);
    f4v ehh1 = *(const f4v*)(b_enc + 16*mt1 + 4*lg);
    f4v ea0 = {0.f,0.f,0.f,0.f}, eb0 = {0.f,0.f,0.f,0.f};
    f4v ea1 = {0.f,0.f,0.f,0.f}, eb1 = {0.f,0.f,0.f,0.f};
    {
        const char* xh = sm + SM_XAHI + agent*336 + 16*lg;
        const char* xl = sm + SM_XALO + agent*336 + 16*lg;
#pragma unroll
        for (int s = 0; s < 5; ++s) {
            s8v bh = *(const s8v*)(xh + 64*s);
            s8v bl = *(const s8v*)(xl + 64*s);
            s8v a0h = *(const s8v*)(wsl + ((0*4 + mt0)*9 + s) * 1024);
            s8v a0l = *(const s8v*)(wsl + ((1*4 + mt0)*9 + s) * 1024);
            s8v a1h = *(const s8v*)(wsl + ((0*4 + mt1)*9 + s) * 1024);
            s8v a1l = *(const s8v*)(wsl + ((1*4 + mt1)*9 + s) * 1024);
            ehh0 = MFMA(a0h, bh, ehh0); ea0 = MFMA(a0h, bl, ea0); eb0 = MFMA(a0l, bh, eb0);
            ehh1 = MFMA(a1h, bh, ehh1); ea1 = MFMA(a1h, bl, ea1); eb1 = MFMA(a1l, bh, eb1);
        }
    }
    __syncthreads();

    // ---- stage X phase B (k 160..287, zero pad >= 275) ----
    {
        char* hrow = sm + SM_XBHI + ag8 * 272;
        char* lrow = sm + SM_XBLO + ag8 * 272;
#pragma unroll
        for (int it = 0; it < 4; ++it) {
            int k0 = 4 * t8 + 32 * it;               // local 0..124
            float x[4];
#pragma unroll
            for (int j2 = 0; j2 < 4; ++j2) {
                int k = 160 + k0 + j2;
                x[j2] = (k < DK) ? xrow[k] : 0.f;
            }
            stage4(hrow, lrow, k0, x[0], x[1], x[2], x[3]);
        }
    }
    __syncthreads();

    // ---- encoder phase B: s = 5..8; then h1 = relu ----
    {
        const char* xh = sm + SM_XBHI + agent*272 + 16*lg;
        const char* xl = sm + SM_XBLO + agent*272 + 16*lg;
#pragma unroll
        for (int s = 5; s < 9; ++s) {
            s8v bh = *(const s8v*)(xh + 64*(s-5));
            s8v bl = *(const s8v*)(xl + 64*(s-5));
            s8v a0h = *(const s8v*)(wsl + ((0*4 + mt0)*9 + s) * 1024);
            s8v a0l = *(const s8v*)(wsl + ((1*4 + mt0)*9 + s) * 1024);
            s8v a1h = *(const s8v*)(wsl + ((0*4 + mt1)*9 + s) * 1024);
            s8v a1l = *(const s8v*)(wsl + ((1*4 + mt1)*9 + s) * 1024);
            ehh0 = MFMA(a0h, bh, ehh0); ea0 = MFMA(a0h, bl, ea0); eb0 = MFMA(a0l, bh, eb0);
            ehh1 = MFMA(a1h, bh, ehh1); ea1 = MFMA(a1h, bl, ea1); eb1 = MFMA(a1l, bh, eb1);
        }
        write_hl4(sm + SM_HHI + agent*144 + (16*mt0 + 4*lg)*2,
                  sm + SM_HLO + agent*144 + (16*mt0 + 4*lg)*2, relu4(ehh0 + ea0 + eb0));
        write_hl4(sm + SM_HHI + agent*144 + (16*mt1 + 4*lg)*2,
                  sm + SM_HLO + agent*144 + (16*mt1 + 4*lg)*2, relu4(ehh1 + ea1 + eb1));
    }
    __syncthreads();

#pragma unroll
    for (int layer = 0; layer < 2; ++layer) {
        const float* bv = layer ? bv2 : bv1;
        const float* bk = layer ? bk2 : bk1;
        const float* bq = layer ? bq2 : bq1;
        const size_t lbase = WSE_SZ + (size_t)layer * 3 * WSL_SZ;

        // ---- QKV; V -> single-bf16 Vt, K/Q -> hi/lo planes ----
        {
            f4v hh[3][2], cx[3][2];
            hh[0][0] = *(const f4v*)(bv + 16*mt0 + 4*lg); hh[0][1] = *(const f4v*)(bv + 16*mt1 + 4*lg);
            hh[1][0] = *(const f4v*)(bk + 16*mt0 + 4*lg); hh[1][1] = *(const f4v*)(bk + 16*mt1 + 4*lg);
            hh[2][0] = *(const f4v*)(bq + 16*mt0 + 4*lg); hh[2][1] = *(const f4v*)(bq + 16*mt1 + 4*lg);
#pragma unroll
            for (int m = 0; m < 3; ++m) { cx[m][0] = f4v{0.f,0.f,0.f,0.f}; cx[m][1] = f4v{0.f,0.f,0.f,0.f}; }
            const char* hH = sm + SM_HHI + agent * 144 + 16*lg;
            const char* hL = sm + SM_HLO + agent * 144 + 16*lg;
#pragma unroll
            for (int s = 0; s < 2; ++s) {
                s8v bh = *(const s8v*)(hH + 64*s);
                s8v bl = *(const s8v*)(hL + 64*s);
#pragma unroll
                for (int m = 0; m < 3; ++m) {
                    const char* wb = wsl + lbase + (size_t)m * WSL_SZ;
                    s8v a0h = *(const s8v*)(wb + ((0*4 + mt0)*2 + s) * 1024);
                    s8v a0l = *(const s8v*)(wb + ((1*4 + mt0)*2 + s) * 1024);
                    s8v a1h = *(const s8v*)(wb + ((0*4 + mt1)*2 + s) * 1024);
                    s8v a1l = *(const s8v*)(wb + ((1*4 + mt1)*2 + s) * 1024);
                    hh[m][0] = MFMA(a0h, bh, hh[m][0]);
                    cx[m][0] = MFMA(a0h, bl, cx[m][0]); cx[m][0] = MFMA(a0l, bh, cx[m][0]);
                    hh[m][1] = MFMA(a1h, bh, hh[m][1]);
                    cx[m][1] = MFMA(a1h, bl, cx[m][1]); cx[m][1] = MFMA(a1l, bh, cx[m][1]);
                }
            }
#pragma unroll
            for (int t = 0; t < 2; ++t) {
                int mt = t ? mt1 : mt0;
                f4v vv = relu4(hh[0][t] + cx[0][t]);
#pragma unroll
                for (int r = 0; r < 4; ++r)
                    *(u16*)(sm + SM_VT + (16*mt + 4*lg + r)*80 + agent*2) = bf_hi(vv[r]);
                write_hl4(sm + SM_KHI + agent*144 + (16*mt + 4*lg)*2,
                          sm + SM_KLO + agent*144 + (16*mt + 4*lg)*2, relu4(hh[1][t] + cx[1][t]));
                write_hl4(sm + SM_QHI + agent*144 + (16*mt + 4*lg)*2,
                          sm + SM_QLO + agent*144 + (16*mt + 4*lg)*2, relu4(hh[2][t] + cx[2][t]));
            }
        }
        __syncthreads();

        // ---- fused scores + masked softmax (waves 0,1) ----
        if (w < 2) {
            f4v shh[2] = {{0.f,0.f,0.f,0.f},{0.f,0.f,0.f,0.f}};
            f4v sca[2] = {{0.f,0.f,0.f,0.f},{0.f,0.f,0.f,0.f}};
            f4v scb[2] = {{0.f,0.f,0.f,0.f},{0.f,0.f,0.f,0.f}};
            const char* qH = sm + SM_QHI + (16*w + lr)*144 + 16*lg;
            const char* qL = sm + SM_QLO + (16*w + lr)*144 + 16*lg;
#pragma unroll
            for (int s = 0; s < 2; ++s) {
                s8v ah = *(const s8v*)(qH + 64*s);
                s8v al = *(const s8v*)(qL + 64*s);
#pragma unroll
                for (int t = 0; t < 2; ++t) {
                    s8v bh = *(const s8v*)(sm + SM_KHI + (16*t + lr)*144 + 16*lg + 64*s);
                    s8v bl = *(const s8v*)(sm + SM_KLO + (16*t + lr)*144 + 16*lg + 64*s);
                    shh[t] = MFMA(ah, bh, shh[t]);
                    sca[t] = MFMA(ah, bl, sca[t]);
                    scb[t] = MFMA(al, bh, scb[t]);
                }
            }
#pragma unroll
            for (int r = 0; r < 4; ++r) {
                int row = 16*w + 4*lg + r;
                float m0 = adjm[r][0], m1 = adjm[r][1];
                float v0 = (shh[0][r] + sca[0][r] + scb[0][r]) * m0 - 9e15f * (1.f - m0);
                float v1 = (shh[1][r] + sca[1][r] + scb[1][r]) * m1 - 9e15f * (1.f - m1);
                float mx = fmaxf(v0, v1);
#pragma unroll
                for (int off = 8; off; off >>= 1) mx = fmaxf(mx, __shfl_xor(mx, off, 16));
                float e0 = __expf(v0 - mx), e1 = __expf(v1 - mx);
                float ssum = e0 + e1;
#pragma unroll
                for (int off = 8; off; off >>= 1) ssum += __shfl_xor(ssum, off, 16);
                float inv = 1.f / ssum;
                *(u16*)(sm + SM_P + row*80 + lr*2)      = bf_hi(e0 * inv);
                *(u16*)(sm + SM_P + row*80 + (16+lr)*2) = bf_hi(e1 * inv);
            }
        }
        __syncthreads();

        // ---- PV: h^T = Vt x P^T (single bf16, K=32) ----
        {
            s8v pb  = *(const s8v*)(sm + SM_P  + (16*ct  + lr)*80 + 16*lg);
            s8v va0 = *(const s8v*)(sm + SM_VT + (16*mt0 + lr)*80 + 16*lg);
            s8v va1 = *(const s8v*)(sm + SM_VT + (16*mt1 + lr)*80 + 16*lg);
            f4v h0 = {0.f,0.f,0.f,0.f}, h1 = {0.f,0.f,0.f,0.f};
            h0 = MFMA(va0, pb, h0);
            h1 = MFMA(va1, pb, h1);
            write_hl4(sm + SM_HHI + agent*144 + (16*mt0 + 4*lg)*2,
                      sm + SM_HLO + agent*144 + (16*mt0 + 4*lg)*2, h0);
            write_hl4(sm + SM_HHI + agent*144 + (16*mt1 + 4*lg)*2,
                      sm + SM_HLO + agent*144 + (16*mt1 + 4*lg)*2, h1);
        }
        __syncthreads();
    }

    // ---- head: q^T = Wqn^T x h3^T (waves 0,1) ----
    if (w < 2) {
        const int ag = 16 * w + lr;
        f4v hacc, cacc = {0.f,0.f,0.f,0.f};
#pragma unroll
        for (int r = 0; r < 4; ++r) { int a = 4*lg + r; hacc[r] = (a < AA) ? bqn[a] : 0.f; }
        const char* hH = sm + SM_HHI + ag * 144 + 16*lg;
        const char* hL = sm + SM_HLO + ag * 144 + 16*lg;
#pragma unroll
        for (int s = 0; s < 2; ++s) {
            s8v bh = *(const s8v*)(hH + 64*s);
            s8v bl = *(const s8v*)(hL + 64*s);
            s8v ah = *(const s8v*)(wsl + WSQN_OFF + (0*2 + s) * 1024);
            s8v al = *(const s8v*)(wsl + WSQN_OFF + (1*2 + s) * 1024);
            hacc = MFMA(ah, bh, hacc);
            cacc = MFMA(ah, bl, cacc); cacc = MFMA(al, bh, cacc);
        }
        f4v acc = hacc + cacc;
        float* op = Out + ((size_t)b * NN + ag) * AA;
#pragma unroll
        for (int r = 0; r < 4; ++r) { int a = 4*lg + r; if (a < AA) op[a] = acc[r]; }
    }
}

__global__ void copy_hidden(const float4* __restrict__ src,
                            float4* __restrict__ dst, int n4)
{
    int i = blockIdx.x * blockDim.x + threadIdx.x;
    int stride = gridDim.x * blockDim.x;
    for (; i < n4; i += stride) dst[i] = src[i];
}

extern "C" void kernel_launch(void* const* d_in, const int* in_sizes, int n_in,
                              void* d_out, int out_size, void* d_ws, size_t ws_size,
                              hipStream_t stream)
{
    const float* X    = (const float*)d_in[0];
    const float* hid  = (const float*)d_in[1];
    const float* adj  = (const float*)d_in[2];
    const float* W_enc = (const float*)d_in[3];
    const float* b_enc = (const float*)d_in[4];
    const float* Wv1 = (const float*)d_in[5];  const float* bv1 = (const float*)d_in[6];
    const float* Wk1 = (const float*)d_in[7];  const float* bk1 = (const float*)d_in[8];
    const float* Wq1 = (const float*)d_in[9];  const float* bq1 = (const float*)d_in[10];
    const float* Wv2 = (const float*)d_in[11]; const float* bv2 = (const float*)d_in[12];
    const float* Wk2 = (const float*)d_in[13]; const float* bk2 = (const float*)d_in[14];
    const float* Wq2 = (const float*)d_in[15]; const float* bq2 = (const float*)d_in[16];
    const float* Wqn = (const float*)d_in[17]; const float* bqn = (const float*)d_in[18];
    float* out = (float*)d_out;
    char* ws = (char*)d_ws;   // needs 176,128 B

    prepack_w<<<43, 256, 0, stream>>>(W_enc, Wv1, Wk1, Wq1, Wv2, Wk2, Wq2, Wqn, ws);

    dgn_mfma<<<NB, 256, 0, stream>>>(X, adj, ws, b_enc,
                                     bv1, bk1, bq1, bv2, bk2, bq2, bqn, out);

    copy_hidden<<<2048, 256, 0, stream>>>((const float4*)hid,
                                          (float4*)(out + Q_ELEMS),
                                          (int)(HID_ELEMS / 4));
}

// Round 6
// 555.267 us; speedup vs baseline: 1.1261x; 1.1261x over previous
//
#include <hip/hip_runtime.h>
#include <hip/hip_bf16.h>

// ---------------- problem constants ----------------
#define NB 16384
#define NN 32
#define DK 275
#define HH 64
#define AA 14
#define Q_ELEMS   ((size_t)NB * NN * AA)
#define HID_ELEMS ((size_t)NB * NN * HH)

typedef unsigned short u16;
typedef unsigned int   u32;
typedef __attribute__((ext_vector_type(8))) short s8v;   // 8 bf16 (4 VGPR)
typedef __attribute__((ext_vector_type(4))) float f4v;   // MFMA acc

#define MFMA(a,b,c) __builtin_amdgcn_mfma_f32_16x16x32_bf16((a),(b),(c),0,0,0)

// native RNE f32->bf16 (pairs fuse to v_cvt_pk_bf16_f32) -- ONLY change vs R3
__device__ __forceinline__ u16 bf_hi(float x){
    return __bfloat16_as_ushort(__float2bfloat16(x));
}
__device__ __forceinline__ float bf_f(u16 h){
    union{u32 u; float f;} v; v.u = ((u32)h) << 16; return v.f;
}

// ---------------- ws (prepacked weight fragments) ----------------
#define WSE_OFF 0
#define WSE_SZ  (2*4*9*1024)
#define WSL_SZ  (2*4*2*1024)
#define WSQN_OFF (WSE_SZ + 6*WSL_SZ)

__global__ void prepack_w(const float* __restrict__ We,
                          const float* __restrict__ Wv1, const float* __restrict__ Wk1, const float* __restrict__ Wq1,
                          const float* __restrict__ Wv2, const float* __restrict__ Wk2, const float* __restrict__ Wq2,
                          const float* __restrict__ Wqn, char* __restrict__ ws)
{
    int gid  = blockIdx.x * 256 + threadIdx.x;
    int slot = gid >> 6, lane = gid & 63;
    const float* W; int K, OUT, STEPS, MT; size_t base; int rem;
    if (slot < 72) { W = We; K = DK; OUT = 64; STEPS = 9; MT = 4; base = WSE_OFF; rem = slot; }
    else if (slot < 168) {
        int q = slot - 72; int mat = q >> 4; rem = q & 15;
        W = mat==0?Wv1 : mat==1?Wk1 : mat==2?Wq1 : mat==3?Wv2 : mat==4?Wk2 : Wq2;
        K = 64; OUT = 64; STEPS = 2; MT = 4; base = WSE_SZ + (size_t)mat * WSL_SZ;
    } else { W = Wqn; K = 64; OUT = AA; STEPS = 2; MT = 1; base = WSQN_OFF; rem = slot - 168; }
    int o  = 16 * (((rem / STEPS) % MT)) + (lane & 15);
    int part = (rem / STEPS) / MT;
    int s  = rem % STEPS;
    int kb = 32 * s + 8 * (lane >> 4);
    u16 h[8];
#pragma unroll
    for (int e = 0; e < 8; ++e) {
        int k = kb + e;
        float x = (k < K && o < OUT) ? W[(size_t)k * OUT + o] : 0.f;
        u16 hi = bf_hi(x);
        h[e] = (part == 0) ? hi : bf_hi(x - bf_f(hi));
    }
    uint4 d;
    d.x = (u32)h[0] | ((u32)h[1] << 16);
    d.y = (u32)h[2] | ((u32)h[3] << 16);
    d.z = (u32)h[4] | ((u32)h[5] << 16);
    d.w = (u32)h[6] | ((u32)h[7] << 16);
    *(uint4*)(ws + base + (size_t)rem * 1024 + (size_t)lane * 16) = d;
}

// ---------------- LDS layout (bytes) -- identical to R3 ----------------
#define SM_XAHI 0
#define SM_XALO 10752
#define SM_XBHI 0
#define SM_XBLO 8704
#define SM_QHI  0
#define SM_QLO  4608
#define SM_KHI  9216
#define SM_KLO  13824
#define SM_VT   18432
#define SM_P    23552
#define SM_HHI  26112
#define SM_HLO  30720
#define SM_ADJ  35328
#define SM_TOT  39424

__device__ __forceinline__ f4v relu4(f4v v){
    f4v r; r[0]=fmaxf(v[0],0.f); r[1]=fmaxf(v[1],0.f);
    r[2]=fmaxf(v[2],0.f); r[3]=fmaxf(v[3],0.f); return r;
}
__device__ __forceinline__ void write_hl4(char* hp, char* lp, f4v v){
    u16 h0=bf_hi(v[0]), h1=bf_hi(v[1]), h2=bf_hi(v[2]), h3=bf_hi(v[3]);
    uint2 hw; hw.x = (u32)h0 | ((u32)h1<<16); hw.y = (u32)h2 | ((u32)h3<<16);
    u16 l0=bf_hi(v[0]-bf_f(h0)), l1=bf_hi(v[1]-bf_f(h1));
    u16 l2=bf_hi(v[2]-bf_f(h2)), l3=bf_hi(v[3]-bf_f(h3));
    uint2 lw; lw.x = (u32)l0 | ((u32)l1<<16); lw.y = (u32)l2 | ((u32)l3<<16);
    *(uint2*)hp = hw; *(uint2*)lp = lw;
}
__device__ __forceinline__ void stage4(char* hrow, char* lrow, int k0,
                                       float x0, float x1, float x2, float x3){
    u16 h0=bf_hi(x0), h1=bf_hi(x1), h2=bf_hi(x2), h3=bf_hi(x3);
    uint2 hw; hw.x=(u32)h0|((u32)h1<<16); hw.y=(u32)h2|((u32)h3<<16);
    u16 l0=bf_hi(x0-bf_f(h0)), l1=bf_hi(x1-bf_f(h1));
    u16 l2=bf_hi(x2-bf_f(h2)), l3=bf_hi(x3-bf_f(h3));
    uint2 lw; lw.x=(u32)l0|((u32)l1<<16); lw.y=(u32)l2|((u32)l3<<16);
    *(uint2*)(hrow + 2*k0) = hw; *(uint2*)(lrow + 2*k0) = lw;
}

__global__ __launch_bounds__(256, 4) void dgn_mfma(
    const float* __restrict__ X, const float* __restrict__ adj,
    const char*  __restrict__ ws,
    const float* __restrict__ b_enc,
    const float* __restrict__ bv1, const float* __restrict__ bk1, const float* __restrict__ bq1,
    const float* __restrict__ bv2, const float* __restrict__ bk2, const float* __restrict__ bq2,
    const float* __restrict__ bqn,
    float* __restrict__ Out)
{
    __shared__ __align__(16) char sm[SM_TOT];
    const int b = blockIdx.x, tid = threadIdx.x;
    const int w = tid >> 6, l = tid & 63, lr = l & 15, lg = l >> 4;
    const int ct  = w & 1;
    const int mt0 = w >> 1, mt1 = (w >> 1) + 2;
    const int agent = 16 * ct + lr;
    const char* wsl = ws + (size_t)l * 16;
    const int t8 = tid & 7, ag8 = tid >> 3;          // staging: 8 threads/agent
    const float* xrow = X + (size_t)b * NN * DK + (size_t)ag8 * DK;

    // ---- stage X phase A (k 0..159) as bf16 hi/lo + adj (LDS, as in R3) ----
    {
        char* hrow = sm + SM_XAHI + ag8 * 336;
        char* lrow = sm + SM_XALO + ag8 * 336;
#pragma unroll
        for (int it = 0; it < 5; ++it) {
            int k0 = 4 * t8 + 32 * it;               // 0..156
            stage4(hrow, lrow, k0, xrow[k0], xrow[k0+1], xrow[k0+2], xrow[k0+3]);
        }
        ((float4*)(sm + SM_ADJ))[tid] = ((const float4*)(adj + (size_t)b * NN * NN))[tid];
    }
    __syncthreads();

    // ---- encoder phase A: s = 0..4 (split accumulator chains) ----
    f4v ehh0 = *(const f4v*)(b_enc + 16*mt0 + 4*lg);
    f4v ehh1 = *(const f4v*)(b_enc + 16*mt1 + 4*lg);
    f4v ea0 = {0.f,0.f,0.f,0.f}, eb0 = {0.f,0.f,0.f,0.f};
    f4v ea1 = {0.f,0.f,0.f,0.f}, eb1 = {0.f,0.f,0.f,0.f};
    {
        const char* xh = sm + SM_XAHI + agent*336 + 16*lg;
        const char* xl = sm + SM_XALO + agent*336 + 16*lg;
#pragma unroll
        for (int s = 0; s < 5; ++s) {
            s8v bh = *(const s8v*)(xh + 64*s);
            s8v bl = *(const s8v*)(xl + 64*s);
            s8v a0h = *(const s8v*)(wsl + ((0*4 + mt0)*9 + s) * 1024);
            s8v a0l = *(const s8v*)(wsl + ((1*4 + mt0)*9 + s) * 1024);
            s8v a1h = *(const s8v*)(wsl + ((0*4 + mt1)*9 + s) * 1024);
            s8v a1l = *(const s8v*)(wsl + ((1*4 + mt1)*9 + s) * 1024);
            ehh0 = MFMA(a0h, bh, ehh0); ea0 = MFMA(a0h, bl, ea0); eb0 = MFMA(a0l, bh, eb0);
            ehh1 = MFMA(a1h, bh, ehh1); ea1 = MFMA(a1h, bl, ea1); eb1 = MFMA(a1l, bh, eb1);
        }
    }
    __syncthreads();

    // ---- stage X phase B (k 160..287, zero pad >= 275) ----
    {
        char* hrow = sm + SM_XBHI + ag8 * 272;
        char* lrow = sm + SM_XBLO + ag8 * 272;
#pragma unroll
        for (int it = 0; it < 4; ++it) {
            int k0 = 4 * t8 + 32 * it;               // local 0..124
            float x[4];
#pragma unroll
            for (int j2 = 0; j2 < 4; ++j2) {
                int k = 160 + k0 + j2;
                x[j2] = (k < DK) ? xrow[k] : 0.f;
            }
            stage4(hrow, lrow, k0, x[0], x[1], x[2], x[3]);
        }
    }
    __syncthreads();

    // ---- encoder phase B: s = 5..8; then h1 = relu ----
    {
        const char* xh = sm + SM_XBHI + agent*272 + 16*lg;
        const char* xl = sm + SM_XBLO + agent*272 + 16*lg;
#pragma unroll
        for (int s = 5; s < 9; ++s) {
            s8v bh = *(const s8v*)(xh + 64*(s-5));
            s8v bl = *(const s8v*)(xl + 64*(s-5));
            s8v a0h = *(const s8v*)(wsl + ((0*4 + mt0)*9 + s) * 1024);
            s8v a0l = *(const s8v*)(wsl + ((1*4 + mt0)*9 + s) * 1024);
            s8v a1h = *(const s8v*)(wsl + ((0*4 + mt1)*9 + s) * 1024);
            s8v a1l = *(const s8v*)(wsl + ((1*4 + mt1)*9 + s) * 1024);
            ehh0 = MFMA(a0h, bh, ehh0); ea0 = MFMA(a0h, bl, ea0); eb0 = MFMA(a0l, bh, eb0);
            ehh1 = MFMA(a1h, bh, ehh1); ea1 = MFMA(a1h, bl, ea1); eb1 = MFMA(a1l, bh, eb1);
        }
        write_hl4(sm + SM_HHI + agent*144 + (16*mt0 + 4*lg)*2,
                  sm + SM_HLO + agent*144 + (16*mt0 + 4*lg)*2, relu4(ehh0 + ea0 + eb0));
        write_hl4(sm + SM_HHI + agent*144 + (16*mt1 + 4*lg)*2,
                  sm + SM_HLO + agent*144 + (16*mt1 + 4*lg)*2, relu4(ehh1 + ea1 + eb1));
    }
    __syncthreads();

#pragma unroll
    for (int layer = 0; layer < 2; ++layer) {
        const float* bv = layer ? bv2 : bv1;
        const float* bk = layer ? bk2 : bk1;
        const float* bq = layer ? bq2 : bq1;
        const size_t lbase = WSE_SZ + (size_t)layer * 3 * WSL_SZ;

        // ---- QKV; V -> single-bf16 Vt, K/Q -> hi/lo planes ----
        {
            f4v hh[3][2], cx[3][2];
            hh[0][0] = *(const f4v*)(bv + 16*mt0 + 4*lg); hh[0][1] = *(const f4v*)(bv + 16*mt1 + 4*lg);
            hh[1][0] = *(const f4v*)(bk + 16*mt0 + 4*lg); hh[1][1] = *(const f4v*)(bk + 16*mt1 + 4*lg);
            hh[2][0] = *(const f4v*)(bq + 16*mt0 + 4*lg); hh[2][1] = *(const f4v*)(bq + 16*mt1 + 4*lg);
#pragma unroll
            for (int m = 0; m < 3; ++m) { cx[m][0] = f4v{0.f,0.f,0.f,0.f}; cx[m][1] = f4v{0.f,0.f,0.f,0.f}; }
            const char* hH = sm + SM_HHI + agent * 144 + 16*lg;
            const char* hL = sm + SM_HLO + agent * 144 + 16*lg;
#pragma unroll
            for (int s = 0; s < 2; ++s) {
                s8v bh = *(const s8v*)(hH + 64*s);
                s8v bl = *(const s8v*)(hL + 64*s);
#pragma unroll
                for (int m = 0; m < 3; ++m) {
                    const char* wb = wsl + lbase + (size_t)m * WSL_SZ;
                    s8v a0h = *(const s8v*)(wb + ((0*4 + mt0)*2 + s) * 1024);
                    s8v a0l = *(const s8v*)(wb + ((1*4 + mt0)*2 + s) * 1024);
                    s8v a1h = *(const s8v*)(wb + ((0*4 + mt1)*2 + s) * 1024);
                    s8v a1l = *(const s8v*)(wb + ((1*4 + mt1)*2 + s) * 1024);
                    hh[m][0] = MFMA(a0h, bh, hh[m][0]);
                    cx[m][0] = MFMA(a0h, bl, cx[m][0]); cx[m][0] = MFMA(a0l, bh, cx[m][0]);
                    hh[m][1] = MFMA(a1h, bh, hh[m][1]);
                    cx[m][1] = MFMA(a1h, bl, cx[m][1]); cx[m][1] = MFMA(a1l, bh, cx[m][1]);
                }
            }
#pragma unroll
            for (int t = 0; t < 2; ++t) {
                int mt = t ? mt1 : mt0;
                f4v vv = relu4(hh[0][t] + cx[0][t]);
#pragma unroll
                for (int r = 0; r < 4; ++r)
                    *(u16*)(sm + SM_VT + (16*mt + 4*lg + r)*80 + agent*2) = bf_hi(vv[r]);
                write_hl4(sm + SM_KHI + agent*144 + (16*mt + 4*lg)*2,
                          sm + SM_KLO + agent*144 + (16*mt + 4*lg)*2, relu4(hh[1][t] + cx[1][t]));
                write_hl4(sm + SM_QHI + agent*144 + (16*mt + 4*lg)*2,
                          sm + SM_QLO + agent*144 + (16*mt + 4*lg)*2, relu4(hh[2][t] + cx[2][t]));
            }
        }
        __syncthreads();

        // ---- fused scores + masked softmax (waves 0,1; adj from LDS) ----
        if (w < 2) {
            f4v shh[2] = {{0.f,0.f,0.f,0.f},{0.f,0.f,0.f,0.f}};
            f4v sca[2] = {{0.f,0.f,0.f,0.f},{0.f,0.f,0.f,0.f}};
            f4v scb[2] = {{0.f,0.f,0.f,0.f},{0.f,0.f,0.f,0.f}};
            const char* qH = sm + SM_QHI + (16*w + lr)*144 + 16*lg;
            const char* qL = sm + SM_QLO + (16*w + lr)*144 + 16*lg;
#pragma unroll
            for (int s = 0; s < 2; ++s) {
                s8v ah = *(const s8v*)(qH + 64*s);
                s8v al = *(const s8v*)(qL + 64*s);
#pragma unroll
                for (int t = 0; t < 2; ++t) {
                    s8v bh = *(const s8v*)(sm + SM_KHI + (16*t + lr)*144 + 16*lg + 64*s);
                    s8v bl = *(const s8v*)(sm + SM_KLO + (16*t + lr)*144 + 16*lg + 64*s);
                    shh[t] = MFMA(ah, bh, shh[t]);
                    sca[t] = MFMA(ah, bl, sca[t]);
                    scb[t] = MFMA(al, bh, scb[t]);
                }
            }
            const float* ad = (const float*)(sm + SM_ADJ);
#pragma unroll
            for (int r = 0; r < 4; ++r) {
                int row = 16*w + 4*lg + r;
                float m0 = ad[row*32 + lr], m1 = ad[row*32 + 16 + lr];
                float v0 = (shh[0][r] + sca[0][r] + scb[0][r]) * m0 - 9e15f * (1.f - m0);
                float v1 = (shh[1][r] + sca[1][r] + scb[1][r]) * m1 - 9e15f * (1.f - m1);
                float mx = fmaxf(v0, v1);
#pragma unroll
                for (int off = 8; off; off >>= 1) mx = fmaxf(mx, __shfl_xor(mx, off, 16));
                float e0 = __expf(v0 - mx), e1 = __expf(v1 - mx);
                float ssum = e0 + e1;
#pragma unroll
                for (int off = 8; off; off >>= 1) ssum += __shfl_xor(ssum, off, 16);
                float inv = 1.f / ssum;
                *(u16*)(sm + SM_P + row*80 + lr*2)      = bf_hi(e0 * inv);
                *(u16*)(sm + SM_P + row*80 + (16+lr)*2) = bf_hi(e1 * inv);
            }
        }
        __syncthreads();

        // ---- PV: h^T = Vt x P^T (single bf16, K=32) ----
        {
            s8v pb  = *(const s8v*)(sm + SM_P  + (16*ct  + lr)*80 + 16*lg);
            s8v va0 = *(const s8v*)(sm + SM_VT + (16*mt0 + lr)*80 + 16*lg);
            s8v va1 = *(const s8v*)(sm + SM_VT + (16*mt1 + lr)*80 + 16*lg);
            f4v h0 = {0.f,0.f,0.f,0.f}, h1 = {0.f,0.f,0.f,0.f};
            h0 = MFMA(va0, pb, h0);
            h1 = MFMA(va1, pb, h1);
            write_hl4(sm + SM_HHI + agent*144 + (16*mt0 + 4*lg)*2,
                      sm + SM_HLO + agent*144 + (16*mt0 + 4*lg)*2, h0);
            write_hl4(sm + SM_HHI + agent*144 + (16*mt1 + 4*lg)*2,
                      sm + SM_HLO + agent*144 + (16*mt1 + 4*lg)*2, h1);
        }
        __syncthreads();
    }

    // ---- head: q^T = Wqn^T x h3^T (waves 0,1) ----
    if (w < 2) {
        const int ag = 16 * w + lr;
        f4v hacc, cacc = {0.f,0.f,0.f,0.f};
#pragma unroll
        for (int r = 0; r < 4; ++r) { int a = 4*lg + r; hacc[r] = (a < AA) ? bqn[a] : 0.f; }
        const char* hH = sm + SM_HHI + ag * 144 + 16*lg;
        const char* hL = sm + SM_HLO + ag * 144 + 16*lg;
#pragma unroll
        for (int s = 0; s < 2; ++s) {
            s8v bh = *(const s8v*)(hH + 64*s);
            s8v bl = *(const s8v*)(hL + 64*s);
            s8v ah = *(const s8v*)(wsl + WSQN_OFF + (0*2 + s) * 1024);
            s8v al = *(const s8v*)(wsl + WSQN_OFF + (1*2 + s) * 1024);
            hacc = MFMA(ah, bh, hacc);
            cacc = MFMA(ah, bl, cacc); cacc = MFMA(al, bh, cacc);
        }
        f4v acc = hacc + cacc;
        float* op = Out + ((size_t)b * NN + ag) * AA;
#pragma unroll
        for (int r = 0; r < 4; ++r) { int a = 4*lg + r; if (a < AA) op[a] = acc[r]; }
    }
}

__global__ void copy_hidden(const float4* __restrict__ src,
                            float4* __restrict__ dst, int n4)
{
    int i = blockIdx.x * blockDim.x + threadIdx.x;
    int stride = gridDim.x * blockDim.x;
    for (; i < n4; i += stride) dst[i] = src[i];
}

extern "C" void kernel_launch(void* const* d_in, const int* in_sizes, int n_in,
                              void* d_out, int out_size, void* d_ws, size_t ws_size,
                              hipStream_t stream)
{
    const float* X    = (const float*)d_in[0];
    const float* hid  = (const float*)d_in[1];
    const float* adj  = (const float*)d_in[2];
    const float* W_enc = (const float*)d_in[3];
    const float* b_enc = (const float*)d_in[4];
    const float* Wv1 = (const float*)d_in[5];  const float* bv1 = (const float*)d_in[6];
    const float* Wk1 = (const float*)d_in[7];  const float* bk1 = (const float*)d_in[8];
    const float* Wq1 = (const float*)d_in[9];  const float* bq1 = (const float*)d_in[10];
    const float* Wv2 = (const float*)d_in[11]; const float* bv2 = (const float*)d_in[12];
    const float* Wk2 = (const float*)d_in[13]; const float* bk2 = (const float*)d_in[14];
    const float* Wq2 = (const float*)d_in[15]; const float* bq2 = (const float*)d_in[16];
    const float* Wqn = (const float*)d_in[17]; const float* bqn = (const float*)d_in[18];
    float* out = (float*)d_out;
    char* ws = (char*)d_ws;   // needs 176,128 B

    prepack_w<<<43, 256, 0, stream>>>(W_enc, Wv1, Wk1, Wq1, Wv2, Wk2, Wq2, Wqn, ws);

    dgn_mfma<<<NB, 256, 0, stream>>>(X, adj, ws, b_enc,
                                     bv1, bk1, bq1, bv2, bk2, bq2, bqn, out);

    copy_hidden<<<2048, 256, 0, stream>>>((const float4*)hid,
                                          (float4*)(out + Q_ELEMS),
                                          (int)(HID_ELEMS / 4));
}

// Round 7
// 467.058 us; speedup vs baseline: 1.3388x; 1.1889x over previous
//
#include <hip/hip_runtime.h>
#include <hip/hip_bf16.h>

// ---------------- problem constants ----------------
#define NB 16384
#define NN 32
#define DK 275
#define HH 64
#define AA 14
#define Q_ELEMS   ((size_t)NB * NN * AA)
#define HID_ELEMS ((size_t)NB * NN * HH)

typedef unsigned short u16;
typedef unsigned int   u32;
typedef __attribute__((ext_vector_type(8))) short s8v;   // 8 bf16 (4 VGPR)
typedef __attribute__((ext_vector_type(4))) float f4v;   // MFMA acc

#define MFMA(a,b,c) __builtin_amdgcn_mfma_f32_16x16x32_bf16((a),(b),(c),0,0,0)

// bit-twiddle RNE f32->bf16 (R3 version — empirically required; native
// v_cvt swap raised FETCH_SIZE +70% and cost +150us, see R6 A/B)
__device__ __forceinline__ u16 bf_hi(float x){
    union{float f; u32 u;} v; v.f = x;
    u32 r = v.u + 0x7fffu + ((v.u >> 16) & 1u);
    return (u16)(r >> 16);
}
__device__ __forceinline__ float bf_f(u16 h){
    union{u32 u; float f;} v; v.u = ((u32)h) << 16; return v.f;
}

// ---------------- ws (prepacked weight fragments) ----------------
#define WSE_OFF 0
#define WSE_SZ  (2*4*9*1024)
#define WSL_SZ  (2*4*2*1024)
#define WSQN_OFF (WSE_SZ + 6*WSL_SZ)

__global__ void prepack_w(const float* __restrict__ We,
                          const float* __restrict__ Wv1, const float* __restrict__ Wk1, const float* __restrict__ Wq1,
                          const float* __restrict__ Wv2, const float* __restrict__ Wk2, const float* __restrict__ Wq2,
                          const float* __restrict__ Wqn, char* __restrict__ ws)
{
    int gid  = blockIdx.x * 256 + threadIdx.x;
    int slot = gid >> 6, lane = gid & 63;
    const float* W; int K, OUT, STEPS, MT; size_t base; int rem;
    if (slot < 72) { W = We; K = DK; OUT = 64; STEPS = 9; MT = 4; base = WSE_OFF; rem = slot; }
    else if (slot < 168) {
        int q = slot - 72; int mat = q >> 4; rem = q & 15;
        W = mat==0?Wv1 : mat==1?Wk1 : mat==2?Wq1 : mat==3?Wv2 : mat==4?Wk2 : Wq2;
        K = 64; OUT = 64; STEPS = 2; MT = 4; base = WSE_SZ + (size_t)mat * WSL_SZ;
    } else { W = Wqn; K = 64; OUT = AA; STEPS = 2; MT = 1; base = WSQN_OFF; rem = slot - 168; }
    int o  = 16 * (((rem / STEPS) % MT)) + (lane & 15);
    int part = (rem / STEPS) / MT;
    int s  = rem % STEPS;
    int kb = 32 * s + 8 * (lane >> 4);
    u16 h[8];
#pragma unroll
    for (int e = 0; e < 8; ++e) {
        int k = kb + e;
        float x = (k < K && o < OUT) ? W[(size_t)k * OUT + o] : 0.f;
        u16 hi = bf_hi(x);
        h[e] = (part == 0) ? hi : bf_hi(x - bf_f(hi));
    }
    uint4 d;
    d.x = (u32)h[0] | ((u32)h[1] << 16);
    d.y = (u32)h[2] | ((u32)h[3] << 16);
    d.z = (u32)h[4] | ((u32)h[5] << 16);
    d.w = (u32)h[6] | ((u32)h[7] << 16);
    *(uint4*)(ws + base + (size_t)rem * 1024 + (size_t)lane * 16) = d;
}

// ---------------- LDS layout (bytes) -- identical to R3 ----------------
#define SM_XAHI 0
#define SM_XALO 10752
#define SM_XBHI 0
#define SM_XBLO 8704
#define SM_QHI  0
#define SM_QLO  4608
#define SM_KHI  9216
#define SM_KLO  13824
#define SM_VT   18432
#define SM_P    23552
#define SM_HHI  26112
#define SM_HLO  30720
#define SM_ADJ  35328
#define SM_TOT  39424

__device__ __forceinline__ f4v relu4(f4v v){
    f4v r; r[0]=fmaxf(v[0],0.f); r[1]=fmaxf(v[1],0.f);
    r[2]=fmaxf(v[2],0.f); r[3]=fmaxf(v[3],0.f); return r;
}
__device__ __forceinline__ void write_hl4(char* hp, char* lp, f4v v){
    u16 h0=bf_hi(v[0]), h1=bf_hi(v[1]), h2=bf_hi(v[2]), h3=bf_hi(v[3]);
    uint2 hw; hw.x = (u32)h0 | ((u32)h1<<16); hw.y = (u32)h2 | ((u32)h3<<16);
    u16 l0=bf_hi(v[0]-bf_f(h0)), l1=bf_hi(v[1]-bf_f(h1));
    u16 l2=bf_hi(v[2]-bf_f(h2)), l3=bf_hi(v[3]-bf_f(h3));
    uint2 lw; lw.x = (u32)l0 | ((u32)l1<<16); lw.y = (u32)l2 | ((u32)l3<<16);
    *(uint2*)hp = hw; *(uint2*)lp = lw;
}
__device__ __forceinline__ void stage4(char* hrow, char* lrow, int k0,
                                       float x0, float x1, float x2, float x3){
    u16 h0=bf_hi(x0), h1=bf_hi(x1), h2=bf_hi(x2), h3=bf_hi(x3);
    uint2 hw; hw.x=(u32)h0|((u32)h1<<16); hw.y=(u32)h2|((u32)h3<<16);
    u16 l0=bf_hi(x0-bf_f(h0)), l1=bf_hi(x1-bf_f(h1));
    u16 l2=bf_hi(x2-bf_f(h2)), l3=bf_hi(x3-bf_f(h3));
    uint2 lw; lw.x=(u32)l0|((u32)l1<<16); lw.y=(u32)l2|((u32)l3<<16);
    *(uint2*)(hrow + 2*k0) = hw; *(uint2*)(lrow + 2*k0) = lw;
}

__global__ __launch_bounds__(256, 4) void dgn_mfma(
    const float* __restrict__ X, const float* __restrict__ hid,
    const float* __restrict__ adj,
    const char*  __restrict__ ws,
    const float* __restrict__ b_enc,
    const float* __restrict__ bv1, const float* __restrict__ bk1, const float* __restrict__ bq1,
    const float* __restrict__ bv2, const float* __restrict__ bk2, const float* __restrict__ bq2,
    const float* __restrict__ bqn,
    float* __restrict__ Out)
{
    __shared__ __align__(16) char sm[SM_TOT];
    const int b = blockIdx.x, tid = threadIdx.x;
    const int w = tid >> 6, l = tid & 63, lr = l & 15, lg = l >> 4;
    const int ct  = w & 1;
    const int mt0 = w >> 1, mt1 = (w >> 1) + 2;
    const int agent = 16 * ct + lr;
    const char* wsl = ws + (size_t)l * 16;
    const int t8 = tid & 7, ag8 = tid >> 3;          // staging: 8 threads/agent
    const float* xrow = X + (size_t)b * NN * DK + (size_t)ag8 * DK;

    // ---- stage X phase A (k 0..159) as bf16 hi/lo + adj ----
    {
        char* hrow = sm + SM_XAHI + ag8 * 336;
        char* lrow = sm + SM_XALO + ag8 * 336;
#pragma unroll
        for (int it = 0; it < 5; ++it) {
            int k0 = 4 * t8 + 32 * it;               // 0..156
            stage4(hrow, lrow, k0, xrow[k0], xrow[k0+1], xrow[k0+2], xrow[k0+3]);
        }
        ((float4*)(sm + SM_ADJ))[tid] = ((const float4*)(adj + (size_t)b * NN * NN))[tid];
    }

    // ---- T14 prestage: issue phase-B X loads NOW (land during encoder A) ----
    float xb[16];
#pragma unroll
    for (int it = 0; it < 4; ++it) {
        int k0 = 160 + 4 * t8 + 32 * it;
#pragma unroll
        for (int j2 = 0; j2 < 4; ++j2)
            xb[4*it + j2] = (k0 + j2 < DK) ? xrow[k0 + j2] : 0.f;
    }
    __syncthreads();

    // ---- encoder phase A: s = 0..4 (split accumulator chains) ----
    f4v ehh0 = *(const f4v*)(b_enc + 16*mt0 + 4*lg);
    f4v ehh1 = *(const f4v*)(b_enc + 16*mt1 + 4*lg);
    f4v ea0 = {0.f,0.f,0.f,0.f}, eb0 = {0.f,0.f,0.f,0.f};
    f4v ea1 = {0.f,0.f,0.f,0.f}, eb1 = {0.f,0.f,0.f,0.f};
    {
        const char* xh = sm + SM_XAHI + agent*336 + 16*lg;
        const char* xl = sm + SM_XALO + agent*336 + 16*lg;
#pragma unroll
        for (int s = 0; s < 5; ++s) {
            s8v bh = *(const s8v*)(xh + 64*s);
            s8v bl = *(const s8v*)(xl + 64*s);
            s8v a0h = *(const s8v*)(wsl + ((0*4 + mt0)*9 + s) * 1024);
            s8v a0l = *(const s8v*)(wsl + ((1*4 + mt0)*9 + s) * 1024);
            s8v a1h = *(const s8v*)(wsl + ((0*4 + mt1)*9 + s) * 1024);
            s8v a1l = *(const s8v*)(wsl + ((1*4 + mt1)*9 + s) * 1024);
            ehh0 = MFMA(a0h, bh, ehh0); ea0 = MFMA(a0h, bl, ea0); eb0 = MFMA(a0l, bh, eb0);
            ehh1 = MFMA(a1h, bh, ehh1); ea1 = MFMA(a1h, bl, ea1); eb1 = MFMA(a1l, bh, eb1);
        }
    }
    __syncthreads();

    // ---- stage X phase B from prestaged registers (k 160..287) ----
    {
        char* hrow = sm + SM_XBHI + ag8 * 272;
        char* lrow = sm + SM_XBLO + ag8 * 272;
#pragma unroll
        for (int it = 0; it < 4; ++it) {
            int k0 = 4 * t8 + 32 * it;               // local 0..124
            stage4(hrow, lrow, k0, xb[4*it], xb[4*it+1], xb[4*it+2], xb[4*it+3]);
        }
    }
    __syncthreads();

    // ---- encoder phase B: s = 5..8; then h1 = relu ----
    {
        const char* xh = sm + SM_XBHI + agent*272 + 16*lg;
        const char* xl = sm + SM_XBLO + agent*272 + 16*lg;
#pragma unroll
        for (int s = 5; s < 9; ++s) {
            s8v bh = *(const s8v*)(xh + 64*(s-5));
            s8v bl = *(const s8v*)(xl + 64*(s-5));
            s8v a0h = *(const s8v*)(wsl + ((0*4 + mt0)*9 + s) * 1024);
            s8v a0l = *(const s8v*)(wsl + ((1*4 + mt0)*9 + s) * 1024);
            s8v a1h = *(const s8v*)(wsl + ((0*4 + mt1)*9 + s) * 1024);
            s8v a1l = *(const s8v*)(wsl + ((1*4 + mt1)*9 + s) * 1024);
            ehh0 = MFMA(a0h, bh, ehh0); ea0 = MFMA(a0h, bl, ea0); eb0 = MFMA(a0l, bh, eb0);
            ehh1 = MFMA(a1h, bh, ehh1); ea1 = MFMA(a1h, bl, ea1); eb1 = MFMA(a1l, bh, eb1);
        }
        write_hl4(sm + SM_HHI + agent*144 + (16*mt0 + 4*lg)*2,
                  sm + SM_HLO + agent*144 + (16*mt0 + 4*lg)*2, relu4(ehh0 + ea0 + eb0));
        write_hl4(sm + SM_HHI + agent*144 + (16*mt1 + 4*lg)*2,
                  sm + SM_HLO + agent*144 + (16*mt1 + 4*lg)*2, relu4(ehh1 + ea1 + eb1));
    }
    __syncthreads();

#pragma unroll
    for (int layer = 0; layer < 2; ++layer) {
        const float* bv = layer ? bv2 : bv1;
        const float* bk = layer ? bk2 : bk1;
        const float* bq = layer ? bq2 : bq1;
        const size_t lbase = WSE_SZ + (size_t)layer * 3 * WSL_SZ;

        // ---- QKV; V -> single-bf16 Vt, K/Q -> hi/lo planes ----
        {
            f4v hh[3][2], cx[3][2];
            hh[0][0] = *(const f4v*)(bv + 16*mt0 + 4*lg); hh[0][1] = *(const f4v*)(bv + 16*mt1 + 4*lg);
            hh[1][0] = *(const f4v*)(bk + 16*mt0 + 4*lg); hh[1][1] = *(const f4v*)(bk + 16*mt1 + 4*lg);
            hh[2][0] = *(const f4v*)(bq + 16*mt0 + 4*lg); hh[2][1] = *(const f4v*)(bq + 16*mt1 + 4*lg);
#pragma unroll
            for (int m = 0; m < 3; ++m) { cx[m][0] = f4v{0.f,0.f,0.f,0.f}; cx[m][1] = f4v{0.f,0.f,0.f,0.f}; }
            const char* hH = sm + SM_HHI + agent * 144 + 16*lg;
            const char* hL = sm + SM_HLO + agent * 144 + 16*lg;
#pragma unroll
            for (int s = 0; s < 2; ++s) {
                s8v bh = *(const s8v*)(hH + 64*s);
                s8v bl = *(const s8v*)(hL + 64*s);
#pragma unroll
                for (int m = 0; m < 3; ++m) {
                    const char* wb = wsl + lbase + (size_t)m * WSL_SZ;
                    s8v a0h = *(const s8v*)(wb + ((0*4 + mt0)*2 + s) * 1024);
                    s8v a0l = *(const s8v*)(wb + ((1*4 + mt0)*2 + s) * 1024);
                    s8v a1h = *(const s8v*)(wb + ((0*4 + mt1)*2 + s) * 1024);
                    s8v a1l = *(const s8v*)(wb + ((1*4 + mt1)*2 + s) * 1024);
                    hh[m][0] = MFMA(a0h, bh, hh[m][0]);
                    cx[m][0] = MFMA(a0h, bl, cx[m][0]); cx[m][0] = MFMA(a0l, bh, cx[m][0]);
                    hh[m][1] = MFMA(a1h, bh, hh[m][1]);
                    cx[m][1] = MFMA(a1h, bl, cx[m][1]); cx[m][1] = MFMA(a1l, bh, cx[m][1]);
                }
            }
#pragma unroll
            for (int t = 0; t < 2; ++t) {
                int mt = t ? mt1 : mt0;
                f4v vv = relu4(hh[0][t] + cx[0][t]);
#pragma unroll
                for (int r = 0; r < 4; ++r)
                    *(u16*)(sm + SM_VT + (16*mt + 4*lg + r)*80 + agent*2) = bf_hi(vv[r]);
                write_hl4(sm + SM_KHI + agent*144 + (16*mt + 4*lg)*2,
                          sm + SM_KLO + agent*144 + (16*mt + 4*lg)*2, relu4(hh[1][t] + cx[1][t]));
                write_hl4(sm + SM_QHI + agent*144 + (16*mt + 4*lg)*2,
                          sm + SM_QLO + agent*144 + (16*mt + 4*lg)*2, relu4(hh[2][t] + cx[2][t]));
            }
        }
        __syncthreads();

        // ---- fused scores + masked softmax (waves 0,1; adj from LDS) ----
        if (w < 2) {
            f4v shh[2] = {{0.f,0.f,0.f,0.f},{0.f,0.f,0.f,0.f}};
            f4v sca[2] = {{0.f,0.f,0.f,0.f},{0.f,0.f,0.f,0.f}};
            f4v scb[2] = {{0.f,0.f,0.f,0.f},{0.f,0.f,0.f,0.f}};
            const char* qH = sm + SM_QHI + (16*w + lr)*144 + 16*lg;
            const char* qL = sm + SM_QLO + (16*w + lr)*144 + 16*lg;
#pragma unroll
            for (int s = 0; s < 2; ++s) {
                s8v ah = *(const s8v*)(qH + 64*s);
                s8v al = *(const s8v*)(qL + 64*s);
#pragma unroll
                for (int t = 0; t < 2; ++t) {
                    s8v bh = *(const s8v*)(sm + SM_KHI + (16*t + lr)*144 + 16*lg + 64*s);
                    s8v bl = *(const s8v*)(sm + SM_KLO + (16*t + lr)*144 + 16*lg + 64*s);
                    shh[t] = MFMA(ah, bh, shh[t]);
                    sca[t] = MFMA(ah, bl, sca[t]);
                    scb[t] = MFMA(al, bh, scb[t]);
                }
            }
            const float* ad = (const float*)(sm + SM_ADJ);
#pragma unroll
            for (int r = 0; r < 4; ++r) {
                int row = 16*w + 4*lg + r;
                float m0 = ad[row*32 + lr], m1 = ad[row*32 + 16 + lr];
                float v0 = (shh[0][r] + sca[0][r] + scb[0][r]) * m0 - 9e15f * (1.f - m0);
                float v1 = (shh[1][r] + sca[1][r] + scb[1][r]) * m1 - 9e15f * (1.f - m1);
                float mx = fmaxf(v0, v1);
#pragma unroll
                for (int off = 8; off; off >>= 1) mx = fmaxf(mx, __shfl_xor(mx, off, 16));
                float e0 = __expf(v0 - mx), e1 = __expf(v1 - mx);
                float ssum = e0 + e1;
#pragma unroll
                for (int off = 8; off; off >>= 1) ssum += __shfl_xor(ssum, off, 16);
                float inv = 1.f / ssum;
                *(u16*)(sm + SM_P + row*80 + lr*2)      = bf_hi(e0 * inv);
                *(u16*)(sm + SM_P + row*80 + (16+lr)*2) = bf_hi(e1 * inv);
            }
        }
        __syncthreads();

        // ---- PV: h^T = Vt x P^T (single bf16, K=32) ----
        {
            s8v pb  = *(const s8v*)(sm + SM_P  + (16*ct  + lr)*80 + 16*lg);
            s8v va0 = *(const s8v*)(sm + SM_VT + (16*mt0 + lr)*80 + 16*lg);
            s8v va1 = *(const s8v*)(sm + SM_VT + (16*mt1 + lr)*80 + 16*lg);
            f4v h0 = {0.f,0.f,0.f,0.f}, h1 = {0.f,0.f,0.f,0.f};
            h0 = MFMA(va0, pb, h0);
            h1 = MFMA(va1, pb, h1);
            write_hl4(sm + SM_HHI + agent*144 + (16*mt0 + 4*lg)*2,
                      sm + SM_HLO + agent*144 + (16*mt0 + 4*lg)*2, h0);
            write_hl4(sm + SM_HHI + agent*144 + (16*mt1 + 4*lg)*2,
                      sm + SM_HLO + agent*144 + (16*mt1 + 4*lg)*2, h1);
        }
        __syncthreads();
    }

    // ---- epilogue: waves 0,1 compute head; waves 2,3 copy hidden slice ----
    if (w < 2) {
        const int ag = 16 * w + lr;
        f4v hacc, cacc = {0.f,0.f,0.f,0.f};
#pragma unroll
        for (int r = 0; r < 4; ++r) { int a = 4*lg + r; hacc[r] = (a < AA) ? bqn[a] : 0.f; }
        const char* hH = sm + SM_HHI + ag * 144 + 16*lg;
        const char* hL = sm + SM_HLO + ag * 144 + 16*lg;
#pragma unroll
        for (int s = 0; s < 2; ++s) {
            s8v bh = *(const s8v*)(hH + 64*s);
            s8v bl = *(const s8v*)(hL + 64*s);
            s8v ah = *(const s8v*)(wsl + WSQN_OFF + (0*2 + s) * 1024);
            s8v al = *(const s8v*)(wsl + WSQN_OFF + (1*2 + s) * 1024);
            hacc = MFMA(ah, bh, hacc);
            cacc = MFMA(ah, bl, cacc); cacc = MFMA(al, bh, cacc);
        }
        f4v acc = hacc + cacc;
        float* op = Out + ((size_t)b * NN + ag) * AA;
#pragma unroll
        for (int r = 0; r < 4; ++r) { int a = 4*lg + r; if (a < AA) op[a] = acc[r]; }
    } else {
        const int tloc = tid - 128;                      // 0..127
        const float4* src = (const float4*)(hid + (size_t)b * NN * HH);
        float4* dst = (float4*)(Out + Q_ELEMS + (size_t)b * NN * HH);
#pragma unroll
        for (int i = 0; i < 4; ++i)
            dst[tloc + 128*i] = src[tloc + 128*i];       // 512 float4 total
    }
}

extern "C" void kernel_launch(void* const* d_in, const int* in_sizes, int n_in,
                              void* d_out, int out_size, void* d_ws, size_t ws_size,
                              hipStream_t stream)
{
    const float* X    = (const float*)d_in[0];
    const float* hid  = (const float*)d_in[1];
    const float* adj  = (const float*)d_in[2];
    const float* W_enc = (const float*)d_in[3];
    const float* b_enc = (const float*)d_in[4];
    const float* Wv1 = (const float*)d_in[5];  const float* bv1 = (const float*)d_in[6];
    const float* Wk1 = (const float*)d_in[7];  const float* bk1 = (const float*)d_in[8];
    const float* Wq1 = (const float*)d_in[9];  const float* bq1 = (const float*)d_in[10];
    const float* Wv2 = (const float*)d_in[11]; const float* bv2 = (const float*)d_in[12];
    const float* Wk2 = (const float*)d_in[13]; const float* bk2 = (const float*)d_in[14];
    const float* Wq2 = (const float*)d_in[15]; const float* bq2 = (const float*)d_in[16];
    const float* Wqn = (const float*)d_in[17]; const float* bqn = (const float*)d_in[18];
    float* out = (float*)d_out;
    char* ws = (char*)d_ws;   // needs 176,128 B

    prepack_w<<<43, 256, 0, stream>>>(W_enc, Wv1, Wk1, Wq1, Wv2, Wk2, Wq2, Wqn, ws);

    dgn_mfma<<<NB, 256, 0, stream>>>(X, hid, adj, ws, b_enc,
                                     bv1, bk1, bq1, bv2, bk2, bq2, bqn, out);
}

// Round 9
// 369.024 us; speedup vs baseline: 1.6944x; 1.2657x over previous
//
#include <hip/hip_runtime.h>
#include <hip/hip_bf16.h>

// ---------------- problem constants ----------------
#define NB 16384
#define NN 32
#define DK 275
#define HH 64
#define AA 14
#define Q_ELEMS   ((size_t)NB * NN * AA)
#define HID_ELEMS ((size_t)NB * NN * HH)

typedef unsigned short u16;
typedef unsigned int   u32;
typedef __attribute__((ext_vector_type(8))) short s8v;   // 8 bf16 (4 VGPR)
typedef __attribute__((ext_vector_type(4))) float f4v;   // MFMA acc

#define MFMA(a,b,c) __builtin_amdgcn_mfma_f32_16x16x32_bf16((a),(b),(c),0,0,0)

// bit-twiddle RNE f32->bf16 (kept for single-bf16 stores & prepack;
// native v_cvt swap raised FETCH_SIZE +70%, +150us — R6 A/B)
__device__ __forceinline__ u16 bf_hi(float x){
    union{float f; u32 u;} v; v.f = x;
    u32 r = v.u + 0x7fffu + ((v.u >> 16) & 1u);
    return (u16)(r >> 16);
}
__device__ __forceinline__ float bf_f(u16 h){
    union{u32 u; float f;} v; v.u = ((u32)h) << 16; return v.f;
}

// ---- truncation-split helpers (3 VALU/value; |hi+lo-x| < 2^-16|x|) ----
__device__ __forceinline__ float thi(float x){
    return __uint_as_float(__float_as_uint(x) & 0xffff0000u);
}
// pack: low16 = a's top half, high16 = b's top half (one v_perm_b32)
__device__ __forceinline__ u32 pk_hi(float a, float b){
    return __builtin_amdgcn_perm(__float_as_uint(b), __float_as_uint(a), 0x07060302u);
}

// ---------------- ws (prepacked weight fragments) ----------------
#define WSE_OFF 0
#define WSE_SZ  (2*4*9*1024)
#define WSL_SZ  (2*4*2*1024)
#define WSQN_OFF (WSE_SZ + 6*WSL_SZ)

__global__ void prepack_w(const float* __restrict__ We,
                          const float* __restrict__ Wv1, const float* __restrict__ Wk1, const float* __restrict__ Wq1,
                          const float* __restrict__ Wv2, const float* __restrict__ Wk2, const float* __restrict__ Wq2,
                          const float* __restrict__ Wqn, char* __restrict__ ws)
{
    int gid  = blockIdx.x * 256 + threadIdx.x;
    int slot = gid >> 6, lane = gid & 63;
    const float* W; int K, OUT, STEPS, MT; size_t base; int rem;
    if (slot < 72) { W = We; K = DK; OUT = 64; STEPS = 9; MT = 4; base = WSE_OFF; rem = slot; }
    else if (slot < 168) {
        int q = slot - 72; int mat = q >> 4; rem = q & 15;
        W = mat==0?Wv1 : mat==1?Wk1 : mat==2?Wq1 : mat==3?Wv2 : mat==4?Wk2 : Wq2;
        K = 64; OUT = 64; STEPS = 2; MT = 4; base = WSE_SZ + (size_t)mat * WSL_SZ;
    } else { W = Wqn; K = 64; OUT = AA; STEPS = 2; MT = 1; base = WSQN_OFF; rem = slot - 168; }
    int o  = 16 * (((rem / STEPS) % MT)) + (lane & 15);
    int part = (rem / STEPS) / MT;
    int s  = rem % STEPS;
    int kb = 32 * s + 8 * (lane >> 4);
    u16 h[8];
#pragma unroll
    for (int e = 0; e < 8; ++e) {
        int k = kb + e;
        float x = (k < K && o < OUT) ? W[(size_t)k * OUT + o] : 0.f;
        u16 hi = bf_hi(x);
        h[e] = (part == 0) ? hi : bf_hi(x - bf_f(hi));
    }
    uint4 d;
    d.x = (u32)h[0] | ((u32)h[1] << 16);
    d.y = (u32)h[2] | ((u32)h[3] << 16);
    d.z = (u32)h[4] | ((u32)h[5] << 16);
    d.w = (u32)h[6] | ((u32)h[7] << 16);
    *(uint4*)(ws + base + (size_t)rem * 1024 + (size_t)lane * 16) = d;
}

// ---------------- LDS layout (bytes) -- identical to R3 ----------------
#define SM_XAHI 0
#define SM_XALO 10752
#define SM_XBHI 0
#define SM_XBLO 8704
#define SM_QHI  0
#define SM_QLO  4608
#define SM_KHI  9216
#define SM_KLO  13824
#define SM_VT   18432
#define SM_P    23552
#define SM_HHI  26112
#define SM_HLO  30720
#define SM_ADJ  35328
#define SM_TOT  39424

__device__ __forceinline__ f4v relu4(f4v v){
    f4v r; r[0]=fmaxf(v[0],0.f); r[1]=fmaxf(v[1],0.f);
    r[2]=fmaxf(v[2],0.f); r[3]=fmaxf(v[3],0.f); return r;
}
// trunc-split hi/lo write: 12 VALU + 2 stores (was ~50 VALU with RNE)
__device__ __forceinline__ void write_hl4(char* hp, char* lp, f4v v){
    float l0 = v[0]-thi(v[0]), l1 = v[1]-thi(v[1]);
    float l2 = v[2]-thi(v[2]), l3 = v[3]-thi(v[3]);
    uint2 hw; hw.x = pk_hi(v[0],v[1]); hw.y = pk_hi(v[2],v[3]);
    uint2 lw; lw.x = pk_hi(l0,l1);     lw.y = pk_hi(l2,l3);
    *(uint2*)hp = hw; *(uint2*)lp = lw;
}
__device__ __forceinline__ void stage4(char* hrow, char* lrow, int k0,
                                       float x0, float x1, float x2, float x3){
    float l0 = x0-thi(x0), l1 = x1-thi(x1), l2 = x2-thi(x2), l3 = x3-thi(x3);
    uint2 hw; hw.x = pk_hi(x0,x1); hw.y = pk_hi(x2,x3);
    uint2 lw; lw.x = pk_hi(l0,l1); lw.y = pk_hi(l2,l3);
    *(uint2*)(hrow + 2*k0) = hw; *(uint2*)(lrow + 2*k0) = lw;
}

__global__ __launch_bounds__(256, 4) void dgn_mfma(
    const float* __restrict__ X, const float* __restrict__ adj,
    const char*  __restrict__ ws,
    const float* __restrict__ b_enc,
    const float* __restrict__ bv1, const float* __restrict__ bk1, const float* __restrict__ bq1,
    const float* __restrict__ bv2, const float* __restrict__ bk2, const float* __restrict__ bq2,
    const float* __restrict__ bqn,
    float* __restrict__ Out)
{
    __shared__ __align__(16) char sm[SM_TOT];
    const int b = blockIdx.x, tid = threadIdx.x;
    const int w = tid >> 6, l = tid & 63, lr = l & 15, lg = l >> 4;
    const int ct  = w & 1;
    const int mt0 = w >> 1, mt1 = (w >> 1) + 2;
    const int agent = 16 * ct + lr;
    const char* wsl = ws + (size_t)l * 16;
    const int t8 = tid & 7, ag8 = tid >> 3;          // staging: 8 threads/agent
    const float* xrow = X + (size_t)b * NN * DK + (size_t)ag8 * DK;

    // ---- stage X phase A (k 0..159) as bf16 hi/lo + adj ----
    {
        char* hrow = sm + SM_XAHI + ag8 * 336;
        char* lrow = sm + SM_XALO + ag8 * 336;
#pragma unroll
        for (int it = 0; it < 5; ++it) {
            int k0 = 4 * t8 + 32 * it;               // 0..156
            stage4(hrow, lrow, k0, xrow[k0], xrow[k0+1], xrow[k0+2], xrow[k0+3]);
        }
        ((float4*)(sm + SM_ADJ))[tid] = ((const float4*)(adj + (size_t)b * NN * NN))[tid];
    }

    // ---- T14 prestage: issue phase-B X loads NOW (land during encoder A) ----
    float xb[16];
#pragma unroll
    for (int it = 0; it < 4; ++it) {
        int k0 = 160 + 4 * t8 + 32 * it;
#pragma unroll
        for (int j2 = 0; j2 < 4; ++j2)
            xb[4*it + j2] = (k0 + j2 < DK) ? xrow[k0 + j2] : 0.f;
    }
    __syncthreads();

    // ---- encoder phase A: s = 0..4 (split accumulator chains) ----
    f4v ehh0 = *(const f4v*)(b_enc + 16*mt0 + 4*lg);
    f4v ehh1 = *(const f4v*)(b_enc + 16*mt1 + 4*lg);
    f4v ea0 = {0.f,0.f,0.f,0.f}, eb0 = {0.f,0.f,0.f,0.f};
    f4v ea1 = {0.f,0.f,0.f,0.f}, eb1 = {0.f,0.f,0.f,0.f};
    {
        const char* xh = sm + SM_XAHI + agent*336 + 16*lg;
        const char* xl = sm + SM_XALO + agent*336 + 16*lg;
#pragma unroll
        for (int s = 0; s < 5; ++s) {
            s8v bh = *(const s8v*)(xh + 64*s);
            s8v bl = *(const s8v*)(xl + 64*s);
            s8v a0h = *(const s8v*)(wsl + ((0*4 + mt0)*9 + s) * 1024);
            s8v a0l = *(const s8v*)(wsl + ((1*4 + mt0)*9 + s) * 1024);
            s8v a1h = *(const s8v*)(wsl + ((0*4 + mt1)*9 + s) * 1024);
            s8v a1l = *(const s8v*)(wsl + ((1*4 + mt1)*9 + s) * 1024);
            ehh0 = MFMA(a0h, bh, ehh0); ea0 = MFMA(a0h, bl, ea0); eb0 = MFMA(a0l, bh, eb0);
            ehh1 = MFMA(a1h, bh, ehh1); ea1 = MFMA(a1h, bl, ea1); eb1 = MFMA(a1l, bh, eb1);
        }
    }
    __syncthreads();

    // ---- stage X phase B from prestaged registers (k 160..287) ----
    {
        char* hrow = sm + SM_XBHI + ag8 * 272;
        char* lrow = sm + SM_XBLO + ag8 * 272;
#pragma unroll
        for (int it = 0; it < 4; ++it) {
            int k0 = 4 * t8 + 32 * it;               // local 0..124
            stage4(hrow, lrow, k0, xb[4*it], xb[4*it+1], xb[4*it+2], xb[4*it+3]);
        }
    }
    __syncthreads();

    // ---- encoder phase B: s = 5..8; then h1 = relu ----
    {
        const char* xh = sm + SM_XBHI + agent*272 + 16*lg;
        const char* xl = sm + SM_XBLO + agent*272 + 16*lg;
#pragma unroll
        for (int s = 5; s < 9; ++s) {
            s8v bh = *(const s8v*)(xh + 64*(s-5));
            s8v bl = *(const s8v*)(xl + 64*(s-5));
            s8v a0h = *(const s8v*)(wsl + ((0*4 + mt0)*9 + s) * 1024);
            s8v a0l = *(const s8v*)(wsl + ((1*4 + mt0)*9 + s) * 1024);
            s8v a1h = *(const s8v*)(wsl + ((0*4 + mt1)*9 + s) * 1024);
            s8v a1l = *(const s8v*)(wsl + ((1*4 + mt1)*9 + s) * 1024);
            ehh0 = MFMA(a0h, bh, ehh0); ea0 = MFMA(a0h, bl, ea0); eb0 = MFMA(a0l, bh, eb0);
            ehh1 = MFMA(a1h, bh, ehh1); ea1 = MFMA(a1h, bl, ea1); eb1 = MFMA(a1l, bh, eb1);
        }
        write_hl4(sm + SM_HHI + agent*144 + (16*mt0 + 4*lg)*2,
                  sm + SM_HLO + agent*144 + (16*mt0 + 4*lg)*2, relu4(ehh0 + ea0 + eb0));
        write_hl4(sm + SM_HHI + agent*144 + (16*mt1 + 4*lg)*2,
                  sm + SM_HLO + agent*144 + (16*mt1 + 4*lg)*2, relu4(ehh1 + ea1 + eb1));
    }
    __syncthreads();

#pragma unroll
    for (int layer = 0; layer < 2; ++layer) {
        const float* bv = layer ? bv2 : bv1;
        const float* bk = layer ? bk2 : bk1;
        const float* bq = layer ? bq2 : bq1;
        const size_t lbase = WSE_SZ + (size_t)layer * 3 * WSL_SZ;

        // ---- QKV; V -> single-bf16 Vt, K/Q -> hi/lo planes ----
        {
            f4v hh[3][2], cx[3][2];
            hh[0][0] = *(const f4v*)(bv + 16*mt0 + 4*lg); hh[0][1] = *(const f4v*)(bv + 16*mt1 + 4*lg);
            hh[1][0] = *(const f4v*)(bk + 16*mt0 + 4*lg); hh[1][1] = *(const f4v*)(bk + 16*mt1 + 4*lg);
            hh[2][0] = *(const f4v*)(bq + 16*mt0 + 4*lg); hh[2][1] = *(const f4v*)(bq + 16*mt1 + 4*lg);
#pragma unroll
            for (int m = 0; m < 3; ++m) { cx[m][0] = f4v{0.f,0.f,0.f,0.f}; cx[m][1] = f4v{0.f,0.f,0.f,0.f}; }
            const char* hH = sm + SM_HHI + agent * 144 + 16*lg;
            const char* hL = sm + SM_HLO + agent * 144 + 16*lg;
#pragma unroll
            for (int s = 0; s < 2; ++s) {
                s8v bh = *(const s8v*)(hH + 64*s);
                s8v bl = *(const s8v*)(hL + 64*s);
#pragma unroll
                for (int m = 0; m < 3; ++m) {
                    const char* wb = wsl + lbase + (size_t)m * WSL_SZ;
                    s8v a0h = *(const s8v*)(wb + ((0*4 + mt0)*2 + s) * 1024);
                    s8v a0l = *(const s8v*)(wb + ((1*4 + mt0)*2 + s) * 1024);
                    s8v a1h = *(const s8v*)(wb + ((0*4 + mt1)*2 + s) * 1024);
                    s8v a1l = *(const s8v*)(wb + ((1*4 + mt1)*2 + s) * 1024);
                    hh[m][0] = MFMA(a0h, bh, hh[m][0]);
                    cx[m][0] = MFMA(a0h, bl, cx[m][0]); cx[m][0] = MFMA(a0l, bh, cx[m][0]);
                    hh[m][1] = MFMA(a1h, bh, hh[m][1]);
                    cx[m][1] = MFMA(a1h, bl, cx[m][1]); cx[m][1] = MFMA(a1l, bh, cx[m][1]);
                }
            }
#pragma unroll
            for (int t = 0; t < 2; ++t) {
                int mt = t ? mt1 : mt0;
                f4v vv = relu4(hh[0][t] + cx[0][t]);
#pragma unroll
                for (int r = 0; r < 4; ++r)
                    *(u16*)(sm + SM_VT + (16*mt + 4*lg + r)*80 + agent*2) = bf_hi(vv[r]);
                write_hl4(sm + SM_KHI + agent*144 + (16*mt + 4*lg)*2,
                          sm + SM_KLO + agent*144 + (16*mt + 4*lg)*2, relu4(hh[1][t] + cx[1][t]));
                write_hl4(sm + SM_QHI + agent*144 + (16*mt + 4*lg)*2,
                          sm + SM_QLO + agent*144 + (16*mt + 4*lg)*2, relu4(hh[2][t] + cx[2][t]));
            }
        }
        __syncthreads();

        // ---- fused scores + masked softmax (waves 0,1; adj from LDS) ----
        if (w < 2) {
            f4v shh[2] = {{0.f,0.f,0.f,0.f},{0.f,0.f,0.f,0.f}};
            f4v sca[2] = {{0.f,0.f,0.f,0.f},{0.f,0.f,0.f,0.f}};
            f4v scb[2] = {{0.f,0.f,0.f,0.f},{0.f,0.f,0.f,0.f}};
            const char* qH = sm + SM_QHI + (16*w + lr)*144 + 16*lg;
            const char* qL = sm + SM_QLO + (16*w + lr)*144 + 16*lg;
#pragma unroll
            for (int s = 0; s < 2; ++s) {
                s8v ah = *(const s8v*)(qH + 64*s);
                s8v al = *(const s8v*)(qL + 64*s);
#pragma unroll
                for (int t = 0; t < 2; ++t) {
                    s8v bh = *(const s8v*)(sm + SM_KHI + (16*t + lr)*144 + 16*lg + 64*s);
                    s8v bl = *(const s8v*)(sm + SM_KLO + (16*t + lr)*144 + 16*lg + 64*s);
                    shh[t] = MFMA(ah, bh, shh[t]);
                    sca[t] = MFMA(ah, bl, sca[t]);
                    scb[t] = MFMA(al, bh, scb[t]);
                }
            }
            const float* ad = (const float*)(sm + SM_ADJ);
#pragma unroll
            for (int r = 0; r < 4; ++r) {
                int row = 16*w + 4*lg + r;
                float m0 = ad[row*32 + lr], m1 = ad[row*32 + 16 + lr];
                float v0 = (shh[0][r] + sca[0][r] + scb[0][r]) * m0 - 9e15f * (1.f - m0);
                float v1 = (shh[1][r] + sca[1][r] + scb[1][r]) * m1 - 9e15f * (1.f - m1);
                float mx = fmaxf(v0, v1);
#pragma unroll
                for (int off = 8; off; off >>= 1) mx = fmaxf(mx, __shfl_xor(mx, off, 16));
                float e0 = __expf(v0 - mx), e1 = __expf(v1 - mx);
                float ssum = e0 + e1;
#pragma unroll
                for (int off = 8; off; off >>= 1) ssum += __shfl_xor(ssum, off, 16);
                float inv = 1.f / ssum;
                *(u16*)(sm + SM_P + row*80 + lr*2)      = bf_hi(e0 * inv);
                *(u16*)(sm + SM_P + row*80 + (16+lr)*2) = bf_hi(e1 * inv);
            }
        }
        __syncthreads();

        // ---- PV: h^T = Vt x P^T (single bf16, K=32) ----
        {
            s8v pb  = *(const s8v*)(sm + SM_P  + (16*ct  + lr)*80 + 16*lg);
            s8v va0 = *(const s8v*)(sm + SM_VT + (16*mt0 + lr)*80 + 16*lg);
            s8v va1 = *(const s8v*)(sm + SM_VT + (16*mt1 + lr)*80 + 16*lg);
            f4v h0 = {0.f,0.f,0.f,0.f}, h1 = {0.f,0.f,0.f,0.f};
            h0 = MFMA(va0, pb, h0);
            h1 = MFMA(va1, pb, h1);
            write_hl4(sm + SM_HHI + agent*144 + (16*mt0 + 4*lg)*2,
                      sm + SM_HLO + agent*144 + (16*mt0 + 4*lg)*2, h0);
            write_hl4(sm + SM_HHI + agent*144 + (16*mt1 + 4*lg)*2,
                      sm + SM_HLO + agent*144 + (16*mt1 + 4*lg)*2, h1);
        }
        __syncthreads();
    }

    // ---- head: q^T = Wqn^T x h3^T (waves 0,1) ----
    if (w < 2) {
        const int ag = 16 * w + lr;
        f4v hacc, cacc = {0.f,0.f,0.f,0.f};
#pragma unroll
        for (int r = 0; r < 4; ++r) { int a = 4*lg + r; hacc[r] = (a < AA) ? bqn[a] : 0.f; }
        const char* hH = sm + SM_HHI + ag * 144 + 16*lg;
        const char* hL = sm + SM_HLO + ag * 144 + 16*lg;
#pragma unroll
        for (int s = 0; s < 2; ++s) {
            s8v bh = *(const s8v*)(hH + 64*s);
            s8v bl = *(const s8v*)(hL + 64*s);
            s8v ah = *(const s8v*)(wsl + WSQN_OFF + (0*2 + s) * 1024);
            s8v al = *(const s8v*)(wsl + WSQN_OFF + (1*2 + s) * 1024);
            hacc = MFMA(ah, bh, hacc);
            cacc = MFMA(ah, bl, cacc); cacc = MFMA(al, bh, cacc);
        }
        f4v acc = hacc + cacc;
        float* op = Out + ((size_t)b * NN + ag) * AA;
#pragma unroll
        for (int r = 0; r < 4; ++r) { int a = 4*lg + r; if (a < AA) op[a] = acc[r]; }
    }
}

__global__ void copy_hidden(const float4* __restrict__ src,
                            float4* __restrict__ dst, int n4)
{
    int i = blockIdx.x * blockDim.x + threadIdx.x;
    int stride = gridDim.x * blockDim.x;
    for (; i < n4; i += stride) dst[i] = src[i];
}

extern "C" void kernel_launch(void* const* d_in, const int* in_sizes, int n_in,
                              void* d_out, int out_size, void* d_ws, size_t ws_size,
                              hipStream_t stream)
{
    const float* X    = (const float*)d_in[0];
    const float* hid  = (const float*)d_in[1];
    const float* adj  = (const float*)d_in[2];
    const float* W_enc = (const float*)d_in[3];
    const float* b_enc = (const float*)d_in[4];
    const float* Wv1 = (const float*)d_in[5];  const float* bv1 = (const float*)d_in[6];
    const float* Wk1 = (const float*)d_in[7];  const float* bk1 = (const float*)d_in[8];
    const float* Wq1 = (const float*)d_in[9];  const float* bq1 = (const float*)d_in[10];
    const float* Wv2 = (const float*)d_in[11]; const float* bv2 = (const float*)d_in[12];
    const float* Wk2 = (const float*)d_in[13]; const float* bk2 = (const float*)d_in[14];
    const float* Wq2 = (const float*)d_in[15]; const float* bq2 = (const float*)d_in[16];
    const float* Wqn = (const float*)d_in[17]; const float* bqn = (const float*)d_in[18];
    float* out = (float*)d_out;
    char* ws = (char*)d_ws;   // needs 176,128 B

    prepack_w<<<43, 256, 0, stream>>>(W_enc, Wv1, Wk1, Wq1, Wv2, Wk2, Wq2, Wqn, ws);

    dgn_mfma<<<NB, 256, 0, stream>>>(X, adj, ws, b_enc,
                                     bv1, bk1, bq1, bv2, bk2, bq2, bqn, out);

    copy_hidden<<<2048, 256, 0, stream>>>((const float4*)hid,
                                          (float4*)(out + Q_ELEMS),
                                          (int)(HID_ELEMS / 4));
}